// Round 15
// baseline (1771.240 us; speedup 1.0000x reference)
//
#include <hip/hip_runtime.h>
#include <hip/hip_fp16.h>
#include <stdint.h>

#define GLOBAL_AS __attribute__((address_space(1)))
#define LDS_AS    __attribute__((address_space(3)))

typedef __attribute__((ext_vector_type(8))) short  short8;   // 8 bf16 = 4 VGPRs
typedef __attribute__((ext_vector_type(4))) float  floatx4;

static constexpr int B_   = 4096;
static constexpr int T_   = 28;
static constexpr int IN_  = 28;
static constexpr int H_   = 1024;
static constexpr int G4_  = 4096;   // 4*H
static constexpr int OUT_ = 10;
static constexpr int NT_  = 16;     // K-tiles of 64 over H=1024

// ---------- small helpers ----------
__device__ __forceinline__ float bf2f(unsigned short u) {
  union { uint32_t i; float f; } v; v.i = ((uint32_t)u) << 16; return v.f;
}
__device__ __forceinline__ unsigned short f2bf(float f) {  // RTNE
  union { float f; uint32_t i; } v; v.f = f;
  uint32_t x = v.i;
  uint32_t lsb = (x >> 16) & 1u;
  x += 0x7fffu + lsb;
  return (unsigned short)(x >> 16);
}
__device__ __forceinline__ float sigm(float x) {
  return __builtin_amdgcn_rcpf(1.f + __builtin_amdgcn_exp2f(-1.4426950408889634f * x));
}
__device__ __forceinline__ float tanh_f(float x) {
  return 1.f - 2.f * __builtin_amdgcn_rcpf(1.f + __builtin_amdgcn_exp2f(2.8853900817779268f * x));
}
__device__ __forceinline__ void stage16(const unsigned short* g, unsigned short* l) {
  __builtin_amdgcn_global_load_lds(
      (const GLOBAL_AS uint32_t*)g, (LDS_AS uint32_t*)l, 16, 0, 0);
}

// ---------- prologue: x -> bf16 [T][B][32] (k padded 28->32 with zeros) ----------
__global__ __launch_bounds__(256) void conv_x_kernel(const float* __restrict__ x,
                                                     unsigned short* __restrict__ xb) {
  int row = blockIdx.x * 256 + threadIdx.x;   // row = t*4096 + b
  int t  = row >> 12;
  int bb = row & 4095;
  const float* src = x + (bb * T_ + t) * IN_;
  unsigned short* dst = xb + row * 32;
#pragma unroll
  for (int k = 0; k < IN_; ++k) dst[k] = f2bf(src[k]);
  dst[28] = 0; dst[29] = 0; dst[30] = 0; dst[31] = 0;
}

// ---------- prologue: W_hh [1024][4096] fp32 -> Wp [4096][1024] bf16, transposed+interleaved ----------
// permuted n = g64*64 + gate*16 + hw  <->  orig col = gate*1024 + g64*16 + hw
__global__ __launch_bounds__(256) void perm_whh_kernel(const float* __restrict__ whh,
                                                       unsigned short* __restrict__ wp) {
  __shared__ float lds[64][17];
  int g64  = blockIdx.x >> 2;
  int gate = blockIdx.x & 3;
  int oc0  = gate * H_ + g64 * 16;
  int n0   = g64 * 64 + gate * 16;
  int tid  = threadIdx.x;
  for (int kc = 0; kc < 16; ++kc) {
    int k0 = kc * 64;
    __syncthreads();
#pragma unroll
    for (int e = 0; e < 4; ++e) {
      int idx = e * 256 + tid;
      int k = idx >> 4, cc = idx & 15;
      lds[k][cc] = whh[(k0 + k) * G4_ + oc0 + cc];
    }
    __syncthreads();
#pragma unroll
    for (int e = 0; e < 4; ++e) {
      int idx = e * 256 + tid;
      int n = idx >> 6, kk = idx & 63;
      wp[(n0 + n) * H_ + k0 + kk] = f2bf(lds[kk][n]);
    }
  }
}

// ---------- prologue: W_ih [28][4096] -> Wip [4096][32] bf16 transposed+interleaved ----------
__global__ __launch_bounds__(256) void perm_wih_kernel(const float* __restrict__ wih,
                                                       unsigned short* __restrict__ wip) {
  __shared__ float lds[28][17];
  int g64  = blockIdx.x >> 2;
  int gate = blockIdx.x & 3;
  int oc0  = gate * H_ + g64 * 16;
  int n0   = g64 * 64 + gate * 16;
  int tid  = threadIdx.x;
  for (int idx = tid; idx < 448; idx += 256) {
    int k = idx >> 4, cc = idx & 15;
    lds[k][cc] = wih[k * G4_ + oc0 + cc];
  }
  __syncthreads();
#pragma unroll
  for (int e = 0; e < 2; ++e) {
    int idx = e * 256 + tid;
    int n = idx >> 5, kk = idx & 31;
    wip[(n0 + n) * 32 + kk] = (kk < IN_) ? f2bf(lds[kk][n]) : (unsigned short)0;
  }
}

// ====== LSTM step: 256x128 tile, single-buffer LDS (48 KB), 2 blocks/CU ======
// EXACT round-9 structure (best measured: 41.1 us): 8 waves (4M x 2N), wave-tile 64x64,
// BK=64, {reads+MFMA} BAR {stage next tile} vmcnt(0) BAR -- phase-separated staging.
// ROUND-15 CHANGE: K-loop STAGGER by co-residency parity. Each block starts its K
// accumulation at logical tile kshift in {0,8} (wrap mod 16). Co-resident blocks then
// run ANTI-PHASE: one block's compute-phase ds_reads fill the LDS port during the
// other's staging drain. parity = (hid ^ (hid>>8)) & 1 separates co-residents under
// both packed-pair and round-robin dispatch. Pure K-sum reorder -- numerics unchanged
// to within fp32 rounding.
__global__ __launch_bounds__(512, 4) void lstm_step_kernel(
    const unsigned short* __restrict__ hprev,   // [B][H] bf16
    const unsigned short* __restrict__ wp,      // [4096][1024] bf16 (permuted^T)
    const unsigned short* __restrict__ xbt,     // [B][32] bf16 (this t)
    const unsigned short* __restrict__ wip,     // [4096][32] bf16 (permuted^T)
    const float* __restrict__ bias,             // [4096] original gate order
    unsigned short* __restrict__ cst,           // [B][H] fp16 cell state
    unsigned short* __restrict__ hnext,         // [B][H] bf16
    int first) {
  __shared__ __align__(16) unsigned short lds[24576];   // 48 KB: A[256][64] | B[128][64]

  const int tid = threadIdx.x;           // 0..511
  const int w   = tid >> 6;              // wave 0..7
  const int l   = tid & 63;
  const int wm  = w >> 1;                // 0..3  (M quarter, 64 rows)
  const int wn  = w & 1;                 // 0..1  (N half, 64 cols)
  const int lc  = l & 15;
  const int lk  = l >> 4;                // 0..3

  // XCD-aware swizzle: 8x8 (bx,by) rectangle per XCD (bijective, 512 = 8 XCD * 64)
  const int hid = blockIdx.x;
  const int xcd = hid & 7, q = hid >> 3;           // q 0..63
  const int bx  = (xcd & 1) * 8 + (q & 7);         // 0..15
  const int by  = (xcd >> 1) * 8 + (q >> 3);       // 0..31
  const int m0  = bx * 256;              // batch rows
  const int n0  = by * 128;              // permuted gate cols

  // K-stagger: co-resident blocks start 8 tiles apart (anti-phase staging)
  const int kshift = ((hid ^ (hid >> 8)) & 1) * 8;

  const int swz  = (lc & 7) << 4;        // B ds_read byte swizzle (128-B rows)
  const int swzx = (lc & 3) << 4;        // x tiles (64-B rows)

  // ---- staging per-thread constants ----
  const int r8  = tid >> 3;              // chunk row 0..63
  const int c8s = ((tid & 7) * 8) ^ ((r8 & 7) * 8);    // pre-swizzled ushort col
  const int rx  = tid >> 2;              // x chunk row 0..127
  const int cxs = ((tid & 3) * 8) ^ ((rx & 3) * 8);    // pre-swizzled (64-B rows)

  auto stageA = [&](int kt, int i) {     // A chunk i: rows i*64.., dst 0..16384 ushorts
    stage16(hprev + (size_t)(m0 + i * 64 + r8) * H_ + kt * 64 + c8s,
            lds + i * 4096 + tid * 8);
  };
  auto stageB = [&](int kt, int j) {     // B chunk j: cols j*64.., dst 16384..24576
    stage16(wp + (size_t)(n0 + j * 64 + r8) * H_ + kt * 64 + c8s,
            lds + 16384 + j * 4096 + tid * 8);
  };
  auto stageXA = [&](int half) {         // XA: [256][32] at ushort 0
    stage16(xbt + (size_t)(m0 + half * 128 + rx) * 32 + cxs,
            lds + half * 4096 + tid * 8);
  };
  auto stageXB = [&]() {                 // XB: [128][32] at ushort 8192
    stage16(wip + (size_t)(n0 + rx) * 32 + cxs, lds + 8192 + tid * 8);
  };
  auto ldsr = [&](int byteoff) -> short8 {
    return *reinterpret_cast<const short8*>(reinterpret_cast<const char*>(lds) + byteoff);
  };

  floatx4 acc[4][4];                     // 64 VGPR: [mf][nf], wave-tile 64x64
#pragma unroll
  for (int i = 0; i < 4; ++i)
#pragma unroll
    for (int j = 0; j < 4; ++j) acc[i][j] = (floatx4){0.f, 0.f, 0.f, 0.f};

  short8 a[4][2];                        // 32 VGPR
  short8 b[2][2];                        // 16 VGPR (two B passes)

#define LOAD_A                                                                       \
  _Pragma("unroll") for (int m_ = 0; m_ < 4; ++m_)                                   \
  _Pragma("unroll") for (int k_ = 0; k_ < 2; ++k_)                                   \
    a[m_][k_] = ldsr((wm * 64 + m_ * 16 + lc) * 128 + ((k_ * 64 + lk * 16) ^ swz));

#define LOAD_B(P)                                                                    \
  _Pragma("unroll") for (int n_ = 0; n_ < 2; ++n_)                                   \
  _Pragma("unroll") for (int k_ = 0; k_ < 2; ++k_)                                   \
    b[n_][k_] = ldsr(32768 + (wn * 64 + ((P) * 2 + n_) * 16 + lc) * 128 +            \
                     ((k_ * 64 + lk * 16) ^ swz));

#define MFMA_P(P)                                                                    \
  __builtin_amdgcn_s_setprio(1);                                                     \
  _Pragma("unroll") for (int m_ = 0; m_ < 4; ++m_)                                   \
  _Pragma("unroll") for (int n_ = 0; n_ < 2; ++n_)                                   \
  _Pragma("unroll") for (int k_ = 0; k_ < 2; ++k_)                                   \
    acc[m_][(P) * 2 + n_] = __builtin_amdgcn_mfma_f32_16x16x32_bf16(                 \
        a[m_][k_], b[n_][k_], acc[m_][(P) * 2 + n_], 0, 0, 0);                       \
  __builtin_amdgcn_s_setprio(0);

#define BAR_ONLY                                                                     \
  __builtin_amdgcn_sched_barrier(0);                                                 \
  __builtin_amdgcn_s_barrier();                                                      \
  __builtin_amdgcn_sched_barrier(0);

#define BAR_VM0                                                                      \
  __builtin_amdgcn_sched_barrier(0);                                                 \
  asm volatile("s_waitcnt vmcnt(0)" ::: "memory");                                   \
  __builtin_amdgcn_s_barrier();                                                      \
  __builtin_amdgcn_sched_barrier(0);

  // ---- x phase: stage, drain, MFMA (K=32) ----
  stageXA(0); stageXA(1); stageXB();
  BAR_VM0
  {
    short8 xb4[4];
#pragma unroll
    for (int nf = 0; nf < 4; ++nf)
      xb4[nf] = ldsr(16384 + (wn * 64 + nf * 16 + lc) * 64 + ((lk * 16) ^ swzx));
    __builtin_amdgcn_s_setprio(1);
#pragma unroll
    for (int mf = 0; mf < 4; ++mf) {
      short8 xa = ldsr((wm * 64 + mf * 16 + lc) * 64 + ((lk * 16) ^ swzx));
#pragma unroll
      for (int nf = 0; nf < 4; ++nf)
        acc[mf][nf] = __builtin_amdgcn_mfma_f32_16x16x32_bf16(xa, xb4[nf], acc[mf][nf], 0, 0, 0);
    }
    __builtin_amdgcn_s_setprio(0);
  }

  if (!first) {
    BAR_ONLY                                   // all waves consumed x (reads retired)
    // ---- first tile stage (logical tile = kshift) ----
#pragma unroll
    for (int i = 0; i < 4; ++i) stageA(kshift, i);
    stageB(kshift, 0); stageB(kshift, 1);
    BAR_VM0
    // ---- main loop: r9 structure; logical tile = (kt + kshift) & 15 ----
    for (int kt = 0; kt < NT_; ++kt) {
      LOAD_A
      LOAD_B(0)
      MFMA_P(0)
      LOAD_B(1)
      MFMA_P(1)
      if (kt + 1 < NT_) {
        const int ktn = (kt + 1 + kshift) & 15;
        BAR_ONLY                               // all waves' tile-kt reads retired
#pragma unroll
        for (int i = 0; i < 4; ++i) stageA(ktn, i);
        stageB(ktn, 0); stageB(ktn, 1);
        BAR_VM0                                // next tile landed
      }
    }
  }

  // ---- epilogue: frag nf == gate; fused LSTM cell update; c in fp16 ----
  const int jj  = (by * 2 + wn) * 16 + lc;     // h column 0..1023
  const float bi  = bias[jj];
  const float bf_ = bias[H_ + jj];
  const float bg_ = bias[2 * H_ + jj];
  const float bo_ = bias[3 * H_ + jj];
#pragma unroll
  for (int mf = 0; mf < 4; ++mf) {
    const int rbase = m0 + wm * 64 + mf * 16 + lk * 4;
#pragma unroll
    for (int r = 0; r < 4; ++r) {
      const size_t idx = (size_t)(rbase + r) * H_ + jj;
      float ig = sigm(acc[mf][0][r] + bi);
      float fg = sigm(acc[mf][1][r] + bf_);
      float gg = tanh_f(acc[mf][2][r] + bg_);
      float og = sigm(acc[mf][3][r] + bo_);
      float cp = first ? 0.f : __half2float(__ushort_as_half(cst[idx]));
      float cn = fg * cp + ig * gg;
      cst[idx] = __half_as_ushort(__float2half(cn));
      hnext[idx] = f2bf(og * tanh_f(cn));
    }
  }
#undef LOAD_A
#undef LOAD_B
#undef MFMA_P
#undef BAR_ONLY
#undef BAR_VM0
}

// ---------- classifier: out = h @ Wc + bc ----------
__global__ __launch_bounds__(256) void cls_kernel(const unsigned short* __restrict__ h,
                                                  const float* __restrict__ wc,
                                                  const float* __restrict__ bc,
                                                  float* __restrict__ out) {
  int w = threadIdx.x >> 6, l = threadIdx.x & 63;
  int row = blockIdx.x * 4 + w;
  float acc[OUT_];
#pragma unroll
  for (int o = 0; o < OUT_; ++o) acc[o] = 0.f;
  const unsigned short* hr = h + row * H_;
  for (int k = l; k < H_; k += 64) {
    float hv = bf2f(hr[k]);
#pragma unroll
    for (int o = 0; o < OUT_; ++o) acc[o] += hv * wc[k * OUT_ + o];
  }
#pragma unroll
  for (int o = 0; o < OUT_; ++o) {
    float v = acc[o];
#pragma unroll
    for (int s = 32; s > 0; s >>= 1) v += __shfl_down(v, s, 64);
    if (l == 0) out[row * OUT_ + o] = v + bc[o];
  }
}

extern "C" void kernel_launch(void* const* d_in, const int* in_sizes, int n_in,
                              void* d_out, int out_size, void* d_ws, size_t ws_size,
                              hipStream_t stream) {
  const float* x    = (const float*)d_in[0];
  const float* wih  = (const float*)d_in[1];
  const float* whh  = (const float*)d_in[2];
  const float* bias = (const float*)d_in[3];
  const float* wc   = (const float*)d_in[4];
  const float* bc   = (const float*)d_in[5];
  float* out = (float*)d_out;

  char* ws = (char*)d_ws;
  unsigned short* wp  = (unsigned short*)(ws);                 //  8 MB  permuted W_hh^T bf16
  unsigned short* wip = (unsigned short*)(ws + 8388608);       //  256KB permuted W_ih^T bf16
  unsigned short* xb  = (unsigned short*)(ws + 8650752);       //  7 MB  x bf16 [T][B][32]
  unsigned short* h0  = (unsigned short*)(ws + 15990784);      //  8 MB
  unsigned short* h1  = (unsigned short*)(ws + 24379392);      //  8 MB
  unsigned short* cst = (unsigned short*)(ws + 32768000);      //  8 MB  fp16 cell state

  hipLaunchKernelGGL(conv_x_kernel,  dim3(448), dim3(256), 0, stream, x, xb);
  hipLaunchKernelGGL(perm_whh_kernel, dim3(256), dim3(256), 0, stream, whh, wp);
  hipLaunchKernelGGL(perm_wih_kernel, dim3(256), dim3(256), 0, stream, wih, wip);

  unsigned short* hb[2] = {h0, h1};
  for (int t = 0; t < T_; ++t) {
    unsigned short* hn = hb[t & 1];
    unsigned short* hp = hb[(t & 1) ^ 1];
    hipLaunchKernelGGL(lstm_step_kernel, dim3(512), dim3(512), 0, stream,
                       hp, wp, xb + (size_t)t * (B_ * 32), wip, bias, cst, hn,
                       (t == 0) ? 1 : 0);
  }
  hipLaunchKernelGGL(cls_kernel, dim3(1024), dim3(256), 0, stream, hb[1], wc, bc, out);
}

// Round 16
// 1019.391 us; speedup vs baseline: 1.7375x; 1.7375x over previous
//
#include <hip/hip_runtime.h>
#include <hip/hip_fp16.h>
#include <stdint.h>

#define GLOBAL_AS __attribute__((address_space(1)))
#define LDS_AS    __attribute__((address_space(3)))

typedef __attribute__((ext_vector_type(8))) short  short8;   // 8 bf16 = 4 VGPRs
typedef __attribute__((ext_vector_type(4))) float  floatx4;

static constexpr int B_   = 4096;
static constexpr int T_   = 28;
static constexpr int IN_  = 28;
static constexpr int H_   = 1024;
static constexpr int G4_  = 4096;   // 4*H
static constexpr int OUT_ = 10;
static constexpr int NT_  = 16;     // h K-tiles of 64 over H=1024 (x adds a 17th tile)

// ---------- small helpers ----------
__device__ __forceinline__ float bf2f(unsigned short u) {
  union { uint32_t i; float f; } v; v.i = ((uint32_t)u) << 16; return v.f;
}
__device__ __forceinline__ unsigned short f2bf(float f) {  // RTNE
  union { float f; uint32_t i; } v; v.f = f;
  uint32_t x = v.i;
  uint32_t lsb = (x >> 16) & 1u;
  x += 0x7fffu + lsb;
  return (unsigned short)(x >> 16);
}
__device__ __forceinline__ float sigm(float x) {
  return __builtin_amdgcn_rcpf(1.f + __builtin_amdgcn_exp2f(-1.4426950408889634f * x));
}
__device__ __forceinline__ float tanh_f(float x) {
  return 1.f - 2.f * __builtin_amdgcn_rcpf(1.f + __builtin_amdgcn_exp2f(2.8853900817779268f * x));
}
__device__ __forceinline__ void stage16(const unsigned short* g, unsigned short* l) {
  __builtin_amdgcn_global_load_lds(
      (const GLOBAL_AS uint32_t*)g, (LDS_AS uint32_t*)l, 16, 0, 0);
}

// ---------- prologue: x -> bf16 [T][B][64] (k padded 28->64 with zeros) ----------
__global__ __launch_bounds__(256) void conv_x_kernel(const float* __restrict__ x,
                                                     unsigned short* __restrict__ xb) {
  int row = blockIdx.x * 256 + threadIdx.x;   // row = t*4096 + b
  int t  = row >> 12;
  int bb = row & 4095;
  const float* src = x + (bb * T_ + t) * IN_;
  unsigned short* dst = xb + (size_t)row * 64;
#pragma unroll
  for (int k = 0; k < IN_; ++k) dst[k] = f2bf(src[k]);
#pragma unroll
  for (int k = IN_; k < 64; ++k) dst[k] = 0;
}

// ---------- prologue: W_hh [1024][4096] fp32 -> Wp [4096][1024] bf16, transposed+interleaved ----------
// permuted n = g64*64 + gate*16 + hw  <->  orig col = gate*1024 + g64*16 + hw
__global__ __launch_bounds__(256) void perm_whh_kernel(const float* __restrict__ whh,
                                                       unsigned short* __restrict__ wp) {
  __shared__ float lds[64][17];
  int g64  = blockIdx.x >> 2;
  int gate = blockIdx.x & 3;
  int oc0  = gate * H_ + g64 * 16;
  int n0   = g64 * 64 + gate * 16;
  int tid  = threadIdx.x;
  for (int kc = 0; kc < 16; ++kc) {
    int k0 = kc * 64;
    __syncthreads();
#pragma unroll
    for (int e = 0; e < 4; ++e) {
      int idx = e * 256 + tid;
      int k = idx >> 4, cc = idx & 15;
      lds[k][cc] = whh[(k0 + k) * G4_ + oc0 + cc];
    }
    __syncthreads();
#pragma unroll
    for (int e = 0; e < 4; ++e) {
      int idx = e * 256 + tid;
      int n = idx >> 6, kk = idx & 63;
      wp[(n0 + n) * H_ + k0 + kk] = f2bf(lds[kk][n]);
    }
  }
}

// ---------- prologue: W_ih [28][4096] -> Wip [4096][64] bf16 transposed+interleaved, padded ----------
__global__ __launch_bounds__(256) void perm_wih_kernel(const float* __restrict__ wih,
                                                       unsigned short* __restrict__ wip) {
  __shared__ float lds[28][17];
  int g64  = blockIdx.x >> 2;
  int gate = blockIdx.x & 3;
  int oc0  = gate * H_ + g64 * 16;
  int n0   = g64 * 64 + gate * 16;
  int tid  = threadIdx.x;
  for (int idx = tid; idx < 448; idx += 256) {
    int k = idx >> 4, cc = idx & 15;
    lds[k][cc] = wih[k * G4_ + oc0 + cc];
  }
  __syncthreads();
#pragma unroll
  for (int e = 0; e < 4; ++e) {               // 16n x 64k = 1024 entries
    int idx = e * 256 + tid;
    int n = idx >> 6, kk = idx & 63;
    wip[(n0 + n) * 64 + kk] = (kk < IN_) ? f2bf(lds[kk][n]) : (unsigned short)0;
  }
}

// ====== LSTM step: 256x128 tile, single-buffer LDS (48 KB), 2 blocks/CU (r9 structure) ======
// 8 waves (4M x 2N), wave-tile 64x64, BK=64. Per tile: {reads+MFMA} BAR {stage next}
// vmcnt(0) BAR (phase-separated staging -- proven best across r10-r15 variants).
// ROUND-16: (1) x folded in as a 17th geometry-identical K-tile (x/Wip padded to 64 k);
// (2) c-state in block-private contiguous layout (2x b128 load + 2x b128 store);
// (3) h-store via post-loop LDS transpose -> 64-B contiguous short8 stores.
__global__ __launch_bounds__(512, 4) void lstm_step_kernel(
    const unsigned short* __restrict__ hprev,   // [B][H] bf16
    const unsigned short* __restrict__ wp,      // [4096][1024] bf16 (permuted^T)
    const unsigned short* __restrict__ xbt,     // [B][64] bf16 (this t, padded)
    const unsigned short* __restrict__ wip,     // [4096][64] bf16 (permuted^T, padded)
    const float* __restrict__ bias,             // [4096] original gate order
    unsigned short* __restrict__ cst,           // [512*512*16] fp16, block-private layout
    unsigned short* __restrict__ hnext,         // [B][H] bf16
    int first) {
  __shared__ __align__(16) unsigned short lds[24576];   // 48 KB: A[256][64] | B[128][64]

  const int tid = threadIdx.x;           // 0..511
  const int w   = tid >> 6;              // wave 0..7
  const int l   = tid & 63;
  const int wm  = w >> 1;                // 0..3  (M quarter, 64 rows)
  const int wn  = w & 1;                 // 0..1  (N half, 64 cols)
  const int lc  = l & 15;
  const int lk  = l >> 4;                // 0..3

  // XCD-aware swizzle: 8x8 (bx,by) rectangle per XCD (bijective, 512 = 8 XCD * 64)
  const int hid = blockIdx.x;
  const int xcd = hid & 7, q = hid >> 3;           // q 0..63
  const int bx  = (xcd & 1) * 8 + (q & 7);         // 0..15
  const int by  = (xcd >> 1) * 8 + (q >> 3);       // 0..31
  const int m0  = bx * 256;              // batch rows
  const int n0  = by * 128;              // permuted gate cols

  const int swz = (lc & 7) << 4;         // ds_read byte swizzle (128-B rows, all tiles)

  // ---- staging per-thread constants ----
  const int r8  = tid >> 3;              // chunk row 0..63
  const int c8s = ((tid & 7) * 8) ^ ((r8 & 7) * 8);    // pre-swizzled ushort col

  auto stageA = [&](int kt, int i) {     // A chunk i: rows i*64.., dst 0..16384 ushorts
    stage16(hprev + (size_t)(m0 + i * 64 + r8) * H_ + kt * 64 + c8s,
            lds + i * 4096 + tid * 8);
  };
  auto stageB = [&](int kt, int j) {     // B chunk j: cols j*64.., dst 16384..24576
    stage16(wp + (size_t)(n0 + j * 64 + r8) * H_ + kt * 64 + c8s,
            lds + 16384 + j * 4096 + tid * 8);
  };
  auto stageXA = [&](int i) {            // x tile: same geometry, stride 64
    stage16(xbt + (size_t)(m0 + i * 64 + r8) * 64 + c8s, lds + i * 4096 + tid * 8);
  };
  auto stageXB = [&](int j) {
    stage16(wip + (size_t)(n0 + j * 64 + r8) * 64 + c8s, lds + 16384 + j * 4096 + tid * 8);
  };
  auto ldsr = [&](int byteoff) -> short8 {
    return *reinterpret_cast<const short8*>(reinterpret_cast<const char*>(lds) + byteoff);
  };

  floatx4 acc[4][4];                     // 64 VGPR: [mf][nf], wave-tile 64x64
#pragma unroll
  for (int i = 0; i < 4; ++i)
#pragma unroll
    for (int j = 0; j < 4; ++j) acc[i][j] = (floatx4){0.f, 0.f, 0.f, 0.f};

  short8 a[4][2];                        // 32 VGPR
  short8 b[2][2];                        // 16 VGPR (two B passes)

#define LOAD_A                                                                       \
  _Pragma("unroll") for (int m_ = 0; m_ < 4; ++m_)                                   \
  _Pragma("unroll") for (int k_ = 0; k_ < 2; ++k_)                                   \
    a[m_][k_] = ldsr((wm * 64 + m_ * 16 + lc) * 128 + ((k_ * 64 + lk * 16) ^ swz));

#define LOAD_B(P)                                                                    \
  _Pragma("unroll") for (int n_ = 0; n_ < 2; ++n_)                                   \
  _Pragma("unroll") for (int k_ = 0; k_ < 2; ++k_)                                   \
    b[n_][k_] = ldsr(32768 + (wn * 64 + ((P) * 2 + n_) * 16 + lc) * 128 +            \
                     ((k_ * 64 + lk * 16) ^ swz));

#define MFMA_P(P)                                                                    \
  __builtin_amdgcn_s_setprio(1);                                                     \
  _Pragma("unroll") for (int m_ = 0; m_ < 4; ++m_)                                   \
  _Pragma("unroll") for (int n_ = 0; n_ < 2; ++n_)                                   \
  _Pragma("unroll") for (int k_ = 0; k_ < 2; ++k_)                                   \
    acc[m_][(P) * 2 + n_] = __builtin_amdgcn_mfma_f32_16x16x32_bf16(                 \
        a[m_][k_], b[n_][k_], acc[m_][(P) * 2 + n_], 0, 0, 0);                       \
  __builtin_amdgcn_s_setprio(0);

#define BAR_ONLY                                                                     \
  __builtin_amdgcn_sched_barrier(0);                                                 \
  __builtin_amdgcn_s_barrier();                                                      \
  __builtin_amdgcn_sched_barrier(0);

#define BAR_VM0                                                                      \
  __builtin_amdgcn_sched_barrier(0);                                                 \
  asm volatile("s_waitcnt vmcnt(0)" ::: "memory");                                   \
  __builtin_amdgcn_s_barrier();                                                      \
  __builtin_amdgcn_sched_barrier(0);

  // ---- stage x tile (tile 0 of the unified loop) ----
  stageXA(0); stageXA(1); stageXA(2); stageXA(3);
  stageXB(0); stageXB(1);
  BAR_VM0

  // ---- unified K-loop: iteration 0 computes x tile; h-tiles staged inside ----
  const int nht = first ? 0 : NT_;
  for (int it = 0; it <= nht; ++it) {
    LOAD_A
    LOAD_B(0)
    MFMA_P(0)
    LOAD_B(1)
    MFMA_P(1)
    if (it < nht) {
      BAR_ONLY                               // all waves' current-tile reads retired
#pragma unroll
      for (int i = 0; i < 4; ++i) stageA(it, i);
      stageB(it, 0); stageB(it, 1);
      BAR_VM0                                // next tile landed
    }
  }

  // ---- epilogue: frag nf == gate; fused LSTM cell update ----
  const int jj  = (by * 2 + wn) * 16 + lc;     // h column 0..1023
  const float bi  = bias[jj];
  const float bf_ = bias[H_ + jj];
  const float bg_ = bias[2 * H_ + jj];
  const float bo_ = bias[3 * H_ + jj];

  const size_t cbase = ((size_t)hid * 512 + tid) * 16;   // block-private c, 16 fp16/thread
  short8 cold0 = {}, cold1 = {};
  if (!first) {
    cold0 = *reinterpret_cast<const short8*>(cst + cbase);
    cold1 = *reinterpret_cast<const short8*>(cst + cbase + 8);
  }
  unsigned short hv[16];
  short8 cs0, cs1;
#pragma unroll
  for (int mf = 0; mf < 4; ++mf)
#pragma unroll
    for (int r = 0; r < 4; ++r) {
      const int e = mf * 4 + r;
      float ig = sigm(acc[mf][0][r] + bi);
      float fg = sigm(acc[mf][1][r] + bf_);
      float gg = tanh_f(acc[mf][2][r] + bg_);
      float og = sigm(acc[mf][3][r] + bo_);
      float cp = first ? 0.f
                       : __half2float(__ushort_as_half(
                             (unsigned short)(e < 8 ? cold0[e] : cold1[e - 8])));
      float cn = fg * cp + ig * gg;
      unsigned short cu = __half_as_ushort(__float2half(cn));
      if (e < 8) cs0[e] = (short)cu; else cs1[e - 8] = (short)cu;
      hv[e] = f2bf(og * tanh_f(cn));
    }
  *reinterpret_cast<short8*>(cst + cbase)     = cs0;   // coalesced 32B/thread
  *reinterpret_cast<short8*>(cst + cbase + 8) = cs1;

  // ---- h store via LDS transpose: [256][32] bf16 tile, then 64-B runs ----
  BAR_ONLY                                   // main-loop LDS reads all retired
#pragma unroll
  for (int mf = 0; mf < 4; ++mf)
#pragma unroll
    for (int r = 0; r < 4; ++r)
      lds[(wm * 64 + mf * 16 + lk * 4 + r) * 32 + wn * 16 + lc] = hv[mf * 4 + r];
  BAR_ONLY
  {
    const int row = tid >> 1, half = tid & 1;
    short8 v0 = *reinterpret_cast<const short8*>(lds + row * 32 + half * 16);
    short8 v1 = *reinterpret_cast<const short8*>(lds + row * 32 + half * 16 + 8);
    unsigned short* dst = hnext + (size_t)(m0 + row) * H_ + by * 32 + half * 16;
    *reinterpret_cast<short8*>(dst)     = v0;
    *reinterpret_cast<short8*>(dst + 8) = v1;
  }
#undef LOAD_A
#undef LOAD_B
#undef MFMA_P
#undef BAR_ONLY
#undef BAR_VM0
}

// ---------- classifier: out = h @ Wc + bc ----------
__global__ __launch_bounds__(256) void cls_kernel(const unsigned short* __restrict__ h,
                                                  const float* __restrict__ wc,
                                                  const float* __restrict__ bc,
                                                  float* __restrict__ out) {
  int w = threadIdx.x >> 6, l = threadIdx.x & 63;
  int row = blockIdx.x * 4 + w;
  float acc[OUT_];
#pragma unroll
  for (int o = 0; o < OUT_; ++o) acc[o] = 0.f;
  const unsigned short* hr = h + row * H_;
  for (int k = l; k < H_; k += 64) {
    float hv = bf2f(hr[k]);
#pragma unroll
    for (int o = 0; o < OUT_; ++o) acc[o] += hv * wc[k * OUT_ + o];
  }
#pragma unroll
  for (int o = 0; o < OUT_; ++o) {
    float v = acc[o];
#pragma unroll
    for (int s = 32; s > 0; s >>= 1) v += __shfl_down(v, s, 64);
    if (l == 0) out[row * OUT_ + o] = v + bc[o];
  }
}

extern "C" void kernel_launch(void* const* d_in, const int* in_sizes, int n_in,
                              void* d_out, int out_size, void* d_ws, size_t ws_size,
                              hipStream_t stream) {
  const float* x    = (const float*)d_in[0];
  const float* wih  = (const float*)d_in[1];
  const float* whh  = (const float*)d_in[2];
  const float* bias = (const float*)d_in[3];
  const float* wc   = (const float*)d_in[4];
  const float* bc   = (const float*)d_in[5];
  float* out = (float*)d_out;

  char* ws = (char*)d_ws;
  unsigned short* wp  = (unsigned short*)(ws);                 //  8 MB   permuted W_hh^T bf16
  unsigned short* wip = (unsigned short*)(ws + 8388608);       //  512 KB permuted W_ih^T bf16 [4096][64]
  unsigned short* xb  = (unsigned short*)(ws + 8912896);       // 14 MB   x bf16 [T][B][64]
  unsigned short* h0  = (unsigned short*)(ws + 23592960);      //  8 MB
  unsigned short* h1  = (unsigned short*)(ws + 31981568);      //  8 MB
  unsigned short* cst = (unsigned short*)(ws + 40370176);      //  8 MB   fp16 c, block-private
  // total ws use: 48,758,784 bytes

  hipLaunchKernelGGL(conv_x_kernel,  dim3(448), dim3(256), 0, stream, x, xb);
  hipLaunchKernelGGL(perm_whh_kernel, dim3(256), dim3(256), 0, stream, whh, wp);
  hipLaunchKernelGGL(perm_wih_kernel, dim3(256), dim3(256), 0, stream, wih, wip);

  unsigned short* hb[2] = {h0, h1};
  for (int t = 0; t < T_; ++t) {
    unsigned short* hn = hb[t & 1];
    unsigned short* hp = hb[(t & 1) ^ 1];
    hipLaunchKernelGGL(lstm_step_kernel, dim3(512), dim3(512), 0, stream,
                       hp, wp, xb + (size_t)t * (B_ * 64), wip, bias, cst, hn,
                       (t == 0) ? 1 : 0);
  }
  hipLaunchKernelGGL(cls_kernel, dim3(1024), dim3(256), 0, stream, hb[1], wc, bc, out);
}